// Round 6
// baseline (396.411 us; speedup 1.0000x reference)
//
#include <hip/hip_runtime.h>
#include <hip/hip_bf16.h>

typedef float f32x4 __attribute__((ext_vector_type(4)));
typedef short short8 __attribute__((ext_vector_type(8)));
typedef __bf16 bf16x8 __attribute__((ext_vector_type(8)));

#define N_TOT 16384
#define FEATS 256
#define BM 128
#define BK 64
#define KSPLIT 4
#define NSTEPS ((N_TOT / KSPLIT) / BK)   // 64
#define LDSA_BYTES (BM * 256)            // fp32 A tile, 256B rows, 32 KiB

static __device__ __forceinline__ ushort f2bf(float f) {
  union { __hip_bfloat16 b; ushort u; } cv;
  cv.b = __float2bfloat16(f);
  return cv.u;
}
static __device__ __forceinline__ float bf2f(ushort u) {
  union { unsigned int i; float f; } c;
  c.i = ((unsigned int)u) << 16;
  return c.f;
}
static __device__ __forceinline__ void gload_lds16(const void* g, void* l) {
  __builtin_amdgcn_global_load_lds((const __attribute__((address_space(1))) unsigned int*)g,
                                   (__attribute__((address_space(3))) unsigned int*)l,
                                   16, 0, 0);
}
static __device__ __forceinline__ bf16x8 cvt8(float4 a, float4 b) {
  short8 r = { (short)f2bf(a.x), (short)f2bf(a.y), (short)f2bf(a.z), (short)f2bf(a.w),
               (short)f2bf(b.x), (short)f2bf(b.y), (short)f2bf(b.z), (short)f2bf(b.w) };
  return __builtin_bit_cast(bf16x8, r);
}

// ---- K0: F2T[o][m] = sum_i feat[m][i]*W[o][i]   (= (features @ W^T)^T, bf16)
// fusion by associativity: out = graph @ F2 + b. 2048 blocks x 64 thr (1 wave):
// wave = 16 m-rows x 128 o-cols, K=256. No LDS; W/feat from L1/L2.
__global__ __launch_bounds__(64) void k_f2t(const float* __restrict__ feat,
                                            const float* __restrict__ W,
                                            ushort* __restrict__ F2T) {
  const int lane = threadIdx.x;
  const int rsel = lane & 15, kg = lane >> 4;
  const int mb = blockIdx.x >> 1;            // 0..1023: m-tile of 16
  const int o0 = (blockIdx.x & 1) * 128;     // o-half
  const int m0 = mb * 16;

  f32x4 acc[8] = {};
#pragma unroll
  for (int ks = 0; ks < 8; ++ks) {
    const int k0 = ks * 32 + kg * 8;
    const float4 fa0 = *(const float4*)(feat + (size_t)(m0 + rsel) * FEATS + k0);
    const float4 fa1 = *(const float4*)(feat + (size_t)(m0 + rsel) * FEATS + k0 + 4);
    const bf16x8 af = cvt8(fa0, fa1);
#pragma unroll
    for (int of = 0; of < 8; ++of) {
      const float4 wb0 = *(const float4*)(W + (size_t)(o0 + of * 16 + rsel) * FEATS + k0);
      const float4 wb1 = *(const float4*)(W + (size_t)(o0 + of * 16 + rsel) * FEATS + k0 + 4);
      acc[of] = __builtin_amdgcn_mfma_f32_16x16x32_bf16(af, cvt8(wb0, wb1), acc[of], 0, 0, 0);
    }
  }
  // D: col=lane&15 -> o within frag, row=kg*4+j -> m within tile
#pragma unroll
  for (int of = 0; of < 8; ++of) {
    ushort4 ov = { f2bf(acc[of][0]), f2bf(acc[of][1]), f2bf(acc[of][2]), f2bf(acc[of][3]) };
    *(ushort4*)(F2T + (size_t)(o0 + of * 16 + rsel) * N_TOT + m0 + kg * 4) = ov;
  }
}

// ---- K1: parts[kb] = graph[:, kchunk] @ F2[kchunk, :]
// 512 thr = 8 waves (2M x 4N), wave tile 64x64. A-ONLY LDS (fp32, 2x32KB -> 2
// blocks/CU); B-frags read directly from L2-resident F2T (XCD-pinned kb chunk).
// BK=64: 256B per graph row per step (DRAM page locality), counted vmcnt.
__global__ __launch_bounds__(512, 4) void k_gemm1(const float* __restrict__ graph,
                                                  const ushort* __restrict__ F2T,
                                                  ushort* __restrict__ parts) {
  __shared__ char lds[2][LDSA_BYTES];   // 64 KiB
  const int tid = threadIdx.x;
  const int lane = tid & 63, w = tid >> 6;
  const int wm = w >> 2, wn = w & 3;
  const int rsel = lane & 15, kg = lane >> 4;

  const int b = blockIdx.x;             // 512 blocks; b&7 = XCD (round-robin)
  const int xcd = b & 7;
  const int kb = xcd >> 1;              // kb chunk pinned to an XCD pair
  const int mi = (b >> 3) | ((xcd & 1) << 6);
  const size_t m0 = (size_t)mi * BM;
  const int kbase = kb * (N_TOT / KSPLIT);
  const int ph = (b * 29) & (NSTEPS - 1);   // per-block k-phase rotation

  // stage A K-tile t (fp32 128 rows x 256B) into buf bf: 4 glds/wave.
  // XOR involution on GLOBAL 16B-chunk index, linear LDS dest (rule #21).
  auto stage = [&](int bf, int t) {
    const int k0 = kbase + t * BK;
    char* ldsA = &lds[bf][0];
#pragma unroll
    for (int j = 0; j < 4; ++j) {
      const int r0 = j * 32 + w * 4;                 // 4 rows per instr
      const int row = r0 + (lane >> 4);
      const int c = (lane & 15) ^ (row & 15);        // 16B chunk within 256B row
      gload_lds16(graph + (m0 + row) * (size_t)N_TOT + k0 + c * 4, ldsA + r0 * 256);
    }
  };

  f32x4 acc[4][4] = {};

  auto compute = [&](int bf, int t) {
    const char* Ab = &lds[bf][0];
    const int kglob = kbase + t * BK;
#pragma unroll
    for (int ksub = 0; ksub < 2; ++ksub) {
      short8 bfr[4];
#pragma unroll
      for (int nf = 0; nf < 4; ++nf) {               // B direct from L2
        const int rowB = wn * 64 + nf * 16 + rsel;
        bfr[nf] = *(const short8*)(F2T + (size_t)rowB * N_TOT + kglob + ksub * 32 + kg * 8);
      }
#pragma unroll
      for (int mf = 0; mf < 4; ++mf) {
        const int row = wm * 64 + mf * 16 + rsel;
        const int cg = ksub * 8 + kg * 2;            // fp32 16B-chunk index
        const float4 a0 = *(const float4*)(Ab + row * 256 + ((cg)     ^ (row & 15)) * 16);
        const float4 a1 = *(const float4*)(Ab + row * 256 + ((cg + 1) ^ (row & 15)) * 16);
        const bf16x8 af = cvt8(a0, a1);
#pragma unroll
        for (int nf = 0; nf < 4; ++nf)
          acc[mf][nf] = __builtin_amdgcn_mfma_f32_16x16x32_bf16(
              af, __builtin_bit_cast(bf16x8, bfr[nf]), acc[mf][nf], 0, 0, 0);
      }
    }
  };

  auto tileof = [&](int s) { return (s + ph) & (NSTEPS - 1); };

  stage(0, tileof(0));
  stage(1, tileof(1));

  for (int s = 0; s < NSTEPS - 2; ++s) {
    asm volatile("s_waitcnt vmcnt(4)" ::: "memory");   // own tile-s glds done
    __builtin_amdgcn_s_barrier();
    compute(s & 1, tileof(s));
    __builtin_amdgcn_s_barrier();                      // all reads of buf done
    stage(s & 1, tileof(s + 2));
    __builtin_amdgcn_sched_barrier(0);
  }
  asm volatile("s_waitcnt vmcnt(4)" ::: "memory");
  __builtin_amdgcn_s_barrier();
  compute((NSTEPS - 2) & 1, tileof(NSTEPS - 2));
  asm volatile("s_waitcnt vmcnt(0)" ::: "memory");
  __builtin_amdgcn_s_barrier();
  compute((NSTEPS - 1) & 1, tileof(NSTEPS - 1));

  // epilogue: bf16 partial store. C/D: col=lane&15, row=kg*4+j
  ushort* p = parts + (size_t)kb * N_TOT * FEATS;
#pragma unroll
  for (int mf = 0; mf < 4; ++mf)
#pragma unroll
    for (int nf = 0; nf < 4; ++nf)
#pragma unroll
      for (int j = 0; j < 4; ++j) {
        const int row = wm * 64 + mf * 16 + kg * 4 + j;
        const int col = wn * 64 + nf * 16 + rsel;
        p[(m0 + row) * FEATS + col] = f2bf(acc[mf][nf][j]);
      }
}

// ---- K2: out = relu(sum_kb parts[kb] + b)
__global__ __launch_bounds__(256) void k_reduce(const ushort* __restrict__ parts,
                                                const float* __restrict__ bias,
                                                float* __restrict__ out) {
  const size_t base = ((size_t)blockIdx.x * 256 + threadIdx.x) * 8;
  const int o0 = (int)(base & (FEATS - 1));
  float s[8] = {0, 0, 0, 0, 0, 0, 0, 0};
#pragma unroll
  for (int p = 0; p < KSPLIT; ++p) {
    const short8 v = *(const short8*)(parts + (size_t)p * N_TOT * FEATS + base);
#pragma unroll
    for (int j = 0; j < 8; ++j) s[j] += bf2f((ushort)v[j]);
  }
  const float4 b0 = *(const float4*)(bias + o0);
  const float4 b1 = *(const float4*)(bias + o0 + 4);
  float4 r0 = { fmaxf(s[0] + b0.x, 0.f), fmaxf(s[1] + b0.y, 0.f),
                fmaxf(s[2] + b0.z, 0.f), fmaxf(s[3] + b0.w, 0.f) };
  float4 r1 = { fmaxf(s[4] + b1.x, 0.f), fmaxf(s[5] + b1.y, 0.f),
                fmaxf(s[6] + b1.z, 0.f), fmaxf(s[7] + b1.w, 0.f) };
  *(float4*)(out + base) = r0;
  *(float4*)(out + base + 4) = r1;
}

extern "C" void kernel_launch(void* const* d_in, const int* in_sizes, int n_in,
                              void* d_out, int out_size, void* d_ws, size_t ws_size,
                              hipStream_t stream) {
  const float* graph = (const float*)d_in[0];
  const float* feat  = (const float*)d_in[1];
  const float* W     = (const float*)d_in[2];
  const float* bias  = (const float*)d_in[3];
  float* out = (float*)d_out;

  char* ws = (char*)d_ws;
  ushort* F2T   = (ushort*)ws;                                 // 8 MiB
  ushort* parts = (ushort*)(ws + (size_t)8 * 1024 * 1024);     // 32 MiB

  k_f2t<<<dim3(2048), 64, 0, stream>>>(feat, W, F2T);
  k_gemm1<<<dim3((N_TOT / BM) * KSPLIT), 512, 0, stream>>>(graph, F2T, parts);
  k_reduce<<<dim3(N_TOT * FEATS / 8 / 256), 256, 0, stream>>>(parts, bias, out);
}